// Round 2
// baseline (51.699 us; speedup 1.0000x reference)
//
#include <hip/hip_runtime.h>

// CRF NLL fused kernel.
// X:[8192,20,128] f32, Y:[8192,20] i32, W:[26,128] f32, T:[26,26] f32 -> scalar f32.
// Phase A: emissions via bf16 MFMA (W register-resident B-frags), scaled by 1/ln2 into LDS.
// Phase B: per-32-lane-group forward recursion in log2 domain (lane = label), ds_swizzle
//          broadcast of s[k], exp2/log2 hardware intrinsics. Block-level reduce + atomicAdd.

typedef float f32x4 __attribute__((ext_vector_type(4)));
typedef __bf16 bf16x8 __attribute__((ext_vector_type(8)));
typedef unsigned short u16x8 __attribute__((ext_vector_type(8)));

#define C_SCALE 1.4426950408889634f  // 1/ln2
#define LN2 0.6931471805599453f

__device__ __forceinline__ unsigned short f2bf(float f) {
    unsigned u = __float_as_uint(f);
    u += 0x7fffu + ((u >> 16) & 1u);   // round-to-nearest-even
    return (unsigned short)(u >> 16);
}

union ABu { u16x8 u; bf16x8 b; };

__device__ __forceinline__ bf16x8 pack_bf8(f32x4 a, f32x4 b) {
    ABu r;
    r.u[0] = f2bf(a[0]); r.u[1] = f2bf(a[1]); r.u[2] = f2bf(a[2]); r.u[3] = f2bf(a[3]);
    r.u[4] = f2bf(b[0]); r.u[5] = f2bf(b[1]); r.u[6] = f2bf(b[2]); r.u[7] = f2bf(b[3]);
    return r.b;
}

__global__ __launch_bounds__(256) void crf_kernel(
    const float* __restrict__ X, const int* __restrict__ Y,
    const float* __restrict__ W, const float* __restrict__ T,
    float* __restrict__ out, int n_elems)
{
    __shared__ float e_lds[320 * 33];   // scaled emissions, stride 33 (bank-conflict-free)
    __shared__ float t_lds[26 * 26];    // T in natural (ln) domain, for edge lookups
    __shared__ float red[16];

    const int tid = threadIdx.x;
    const int w   = tid >> 6;          // wave id 0..3
    const int l   = tid & 63;          // lane

    // stage T (natural domain)
    for (int i = tid; i < 676; i += 256) t_lds[i] = T[i];

    // ---- W as bf16 B-fragments (loaded once, register resident) ----
    // B layout (16x16x32): col = lane&15, k = (lane>>4)*8 + j  -> B[k][col] = W[col][k]
    ABu bfrag[4][2];
    {
        const int c0   = l & 15;
        const int koff = (l >> 4) * 8;
        #pragma unroll
        for (int kk = 0; kk < 4; ++kk) {
            #pragma unroll
            for (int nt = 0; nt < 2; ++nt) {
                const int col = nt * 16 + c0;
                ABu f;
                if (col < 26) {
                    const float* wp = W + col * 128 + kk * 32 + koff;
                    f32x4 w0 = *(const f32x4*)(wp);
                    f32x4 w1 = *(const f32x4*)(wp + 4);
                    f.b = pack_bf8(w0, w1);
                } else {
                    #pragma unroll
                    for (int j = 0; j < 8; ++j) f.u[j] = 0;
                }
                bfrag[kk][nt] = f;
            }
        }
    }

    // ---- T columns (log2-scaled) in registers for the recursion ----
    // lane j (j = lane&31 < 26) holds T2[k] = T[k][j] / ln2
    float T2[26];
    {
        int j = l & 31; if (j > 25) j = 0;
        #pragma unroll
        for (int k = 0; k < 26; ++k) T2[k] = T[k * 26 + j] * C_SCALE;
    }

    // ---- Phase A: emissions for this block's 16 batch elems (320 rows) ----
    {
        const int rbase = w * 80;          // wave's 80 rows (4 elems)
        const int c0    = l & 15;
        const int kg    = l >> 4;
        for (int t = 0; t < 5; ++t) {
            const int row_local = rbase + t * 16 + c0;
            const float* xp = X + ((long)blockIdx.x * 320 + row_local) * 128 + kg * 8;
            f32x4 acc0 = {0.f, 0.f, 0.f, 0.f};
            f32x4 acc1 = {0.f, 0.f, 0.f, 0.f};
            #pragma unroll
            for (int kk = 0; kk < 4; ++kk) {
                f32x4 x0 = *(const f32x4*)(xp + kk * 32);
                f32x4 x1 = *(const f32x4*)(xp + kk * 32 + 4);
                bf16x8 a = pack_bf8(x0, x1);
                acc0 = __builtin_amdgcn_mfma_f32_16x16x32_bf16(a, bfrag[kk][0].b, acc0, 0, 0, 0);
                acc1 = __builtin_amdgcn_mfma_f32_16x16x32_bf16(a, bfrag[kk][1].b, acc1, 0, 0, 0);
            }
            // C/D layout: col = lane&15, row = (lane>>4)*4 + i   [m89-verified]
            #pragma unroll
            for (int i = 0; i < 4; ++i) {
                const int rr = rbase + t * 16 + kg * 4 + i;
                e_lds[rr * 33 + c0]      = acc0[i] * C_SCALE;
                e_lds[rr * 33 + 16 + c0] = acc1[i] * C_SCALE;
            }
        }
    }
    __syncthreads();

    // ---- Phase B: forward recursion (log2 domain), 2 elems per wave concurrently ----
    const int g  = l >> 5;            // group within wave
    const int kl = l & 31;            // label lane
    const bool act = kl < 26;
    const int jj = act ? kl : 0;

    for (int pass = 0; pass < 2; ++pass) {
        const int el = w * 4 + pass * 2 + g;   // block-local elem 0..15
        const int b  = blockIdx.x * 16 + el;
        const int base = el * 20;

        float alpha2 = 0.f;
        #pragma unroll 1
        for (int m = 0; m < 19; ++m) {
            const float s = e_lds[(base + m) * 33 + jj] + alpha2;
            const int si = __float_as_int(s);
            float vv[26];
            float mx = -3.4e38f;
            // broadcast s[k] within each 32-lane group (bit-mode: and=0, or=k, xor=0;
            // lane bit 5 is preserved by HW automatically)
            #define CRF_STEP(k) { \
                float sk = __int_as_float(__builtin_amdgcn_ds_swizzle(si, ((k) << 5))); \
                float v = sk + T2[k]; vv[k] = v; mx = fmaxf(mx, v); }
            CRF_STEP(0)  CRF_STEP(1)  CRF_STEP(2)  CRF_STEP(3)  CRF_STEP(4)
            CRF_STEP(5)  CRF_STEP(6)  CRF_STEP(7)  CRF_STEP(8)  CRF_STEP(9)
            CRF_STEP(10) CRF_STEP(11) CRF_STEP(12) CRF_STEP(13) CRF_STEP(14)
            CRF_STEP(15) CRF_STEP(16) CRF_STEP(17) CRF_STEP(18) CRF_STEP(19)
            CRF_STEP(20) CRF_STEP(21) CRF_STEP(22) CRF_STEP(23) CRF_STEP(24)
            CRF_STEP(25)
            #undef CRF_STEP
            float sum = 0.f;
            #pragma unroll
            for (int k = 0; k < 26; ++k) sum += __builtin_amdgcn_exp2f(vv[k] - mx);
            alpha2 = mx + __builtin_amdgcn_logf(sum);   // v_log_f32 = log2
        }

        // log Z (log2 domain): LSE over labels within the 32-lane group
        float s = act ? (e_lds[(base + 19) * 33 + jj] + alpha2) : -3.4e38f;
        float mx = s;
        #pragma unroll
        for (int d = 1; d <= 16; d <<= 1) mx = fmaxf(mx, __shfl_xor(mx, d, 64));
        float ex = act ? __builtin_amdgcn_exp2f(s - mx) : 0.f;
        #pragma unroll
        for (int d = 1; d <= 16; d <<= 1) ex += __shfl_xor(ex, d, 64);
        const float logZ2 = mx + __builtin_amdgcn_logf(ex);

        // node (scaled emissions from LDS) + edge (natural T, rescaled)
        int ym = 0;
        float contrib = 0.f;
        if (kl < 20) {
            ym = Y[b * 20 + kl];
            contrib = e_lds[(base + kl) * 33 + ym];   // already * 1/ln2
        }
        const int yn = __shfl(ym, l + 1, 64);
        if (kl < 19) contrib += t_lds[ym * 26 + yn] * C_SCALE;
        #pragma unroll
        for (int d = 1; d <= 16; d <<= 1) contrib += __shfl_xor(contrib, d, 64);

        const float nll = (logZ2 - contrib) * LN2;    // logZ - node - edge
        if (kl == 0) red[el] = nll;
    }
    __syncthreads();

    if (tid == 0) {
        float ssum = 0.f;
        #pragma unroll
        for (int i = 0; i < 16; ++i) ssum += red[i];
        atomicAdd(out, ssum);
    }
}

extern "C" void kernel_launch(void* const* d_in, const int* in_sizes, int n_in,
                              void* d_out, int out_size, void* d_ws, size_t ws_size,
                              hipStream_t stream) {
    const float* X = (const float*)d_in[0];
    const int*   Y = (const int*)d_in[1];
    const float* W = (const float*)d_in[2];
    const float* T = (const float*)d_in[3];
    float* out = (float*)d_out;

    const int B = in_sizes[1] / 20;        // 8192
    const int nblocks = B / 16;            // 512

    hipMemsetAsync(out, 0, sizeof(float), stream);
    crf_kernel<<<nblocks, 256, 0, stream>>>(X, Y, W, T, out, B);
}

// Round 4
// 39.841 us; speedup vs baseline: 1.2976x; 1.2976x over previous
//
#include <hip/hip_runtime.h>

// CRF NLL fused kernel, v3: round-2 phase A (verified) + MFMA-matvec recursion.
// Phase A: emissions e=(X·W^T)/ln2 f32 into LDS via bf16 MFMA (all 4 waves).
// Phase B: wave 0 only; alpha'[j] = mx + log2(sum_k 2^(s_k-mx) * E[k,j]) with
//   E = 2^(T/ln2) baked into k-permuted A-fragments so the p-vector (B operand)
//   needs NO cross-lane permute: one wave advances all 16 elems per step.

typedef float f32x4 __attribute__((ext_vector_type(4)));
typedef __bf16 bf16x8 __attribute__((ext_vector_type(8)));

#define C_SCALE 1.4426950408889634f  // 1/ln2
#define LN2 0.6931471805599453f
#define NEGF -3.0e38f

__device__ __forceinline__ unsigned short f2bf(float f) {
    unsigned u = __float_as_uint(f);
    u += 0x7fffu + ((u >> 16) & 1u);   // RNE
    return (unsigned short)(u >> 16);
}

union ABu { unsigned int w[4]; bf16x8 b; unsigned short u[8]; };

__device__ __forceinline__ bf16x8 pack_bf8(f32x4 a, f32x4 b) {
    ABu r;
    r.u[0] = f2bf(a[0]); r.u[1] = f2bf(a[1]); r.u[2] = f2bf(a[2]); r.u[3] = f2bf(a[3]);
    r.u[4] = f2bf(b[0]); r.u[5] = f2bf(b[1]); r.u[6] = f2bf(b[2]); r.u[7] = f2bf(b[3]);
    return r.b;
}

__global__ __launch_bounds__(256) void crf_kernel(
    const float* __restrict__ X, const int* __restrict__ Y,
    const float* __restrict__ W, const float* __restrict__ T,
    float* __restrict__ out, int n_elems)
{
    __shared__ float e_lds[320 * 33];   // scaled emissions, stride 33
    __shared__ float t_lds[26 * 26];    // T natural domain

    const int tid = threadIdx.x;
    const int w   = tid >> 6;
    const int l   = tid & 63;

    for (int i = tid; i < 676; i += 256) t_lds[i] = T[i];

    // ---- Phase A (identical to round-2 verified version) ----
    {
        const int c0 = l & 15, kg = l >> 4;
        ABu bfrag[4][2];
        const int koff = kg * 8;
        #pragma unroll
        for (int kk = 0; kk < 4; ++kk) {
            #pragma unroll
            for (int nt = 0; nt < 2; ++nt) {
                const int col = nt * 16 + c0;
                ABu f;
                if (col < 26) {
                    const float* wp = W + col * 128 + kk * 32 + koff;
                    f32x4 w0 = *(const f32x4*)wp;
                    f32x4 w1 = *(const f32x4*)(wp + 4);
                    f.b = pack_bf8(w0, w1);
                } else {
                    f.w[0] = f.w[1] = f.w[2] = f.w[3] = 0u;
                }
                bfrag[kk][nt] = f;
            }
        }
        const int rbase = w * 80;
        for (int t = 0; t < 5; ++t) {
            const int row_local = rbase + t * 16 + c0;
            const float* xp = X + ((long)blockIdx.x * 320 + row_local) * 128 + kg * 8;
            f32x4 acc0 = {0.f,0.f,0.f,0.f}, acc1 = {0.f,0.f,0.f,0.f};
            #pragma unroll
            for (int kk = 0; kk < 4; ++kk) {
                f32x4 x0 = *(const f32x4*)(xp + kk * 32);
                f32x4 x1 = *(const f32x4*)(xp + kk * 32 + 4);
                bf16x8 a = pack_bf8(x0, x1);
                acc0 = __builtin_amdgcn_mfma_f32_16x16x32_bf16(a, bfrag[kk][0].b, acc0, 0, 0, 0);
                acc1 = __builtin_amdgcn_mfma_f32_16x16x32_bf16(a, bfrag[kk][1].b, acc1, 0, 0, 0);
            }
            #pragma unroll
            for (int i = 0; i < 4; ++i) {
                const int rr = rbase + t * 16 + kg * 4 + i;
                e_lds[rr * 33 + c0]      = acc0[i] * C_SCALE;
                e_lds[rr * 33 + 16 + c0] = acc1[i] * C_SCALE;
            }
        }
    }
    __syncthreads();

    if (w != 0) return;

    // ---- Phase B: MFMA-matvec recursion, wave 0, 16 elems in parallel ----
    const int g = l >> 4, c = l & 15;

    // A-fragments: A[m][k'] = E[pi(k')][m], pi(8g+jj) = 4g+(jj&3)+16*(jj>>2).
    ABu A0, A1;
    #pragma unroll
    for (int jj = 0; jj < 8; ++jj) {
        const int kp = 4 * g + (jj & 3) + ((jj >> 2) << 4);
        float v0 = 0.f, v1 = 0.f;
        if (kp < 26) {
            v0 = __builtin_amdgcn_exp2f(t_lds[kp * 26 + c] * C_SCALE);
            if (16 + c < 26) v1 = __builtin_amdgcn_exp2f(t_lds[kp * 26 + 16 + c] * C_SCALE);
        }
        A0.u[jj] = f2bf(v0);
        A1.u[jj] = f2bf(v1);
    }

    const bool ok0 = (16 + 4 * g + 0) < 26;
    const bool ok1 = (16 + 4 * g + 1) < 26;
    const bool ok2 = (16 + 4 * g + 2) < 26;
    const bool ok3 = (16 + 4 * g + 3) < 26;

    const float* eb = e_lds + c * 660 + 4 * g;   // c*20*33, this lane's label quad

    f32x4 s0, s1;
    #pragma unroll
    for (int i = 0; i < 4; ++i) { s0[i] = eb[i]; s1[i] = eb[16 + i]; }
    if (!ok0) s1[0] = NEGF;
    if (!ok1) s1[1] = NEGF;
    if (!ok2) s1[2] = NEGF;
    if (!ok3) s1[3] = NEGF;

    const f32x4 z = {0.f, 0.f, 0.f, 0.f};
    #pragma unroll 1
    for (int m = 0; m < 19; ++m) {
        float mx = fmaxf(fmaxf(fmaxf(s0[0], s0[1]), fmaxf(s0[2], s0[3])),
                         fmaxf(fmaxf(s1[0], s1[1]), fmaxf(s1[2], s1[3])));
        mx = fmaxf(mx, __shfl_xor(mx, 16, 64));
        mx = fmaxf(mx, __shfl_xor(mx, 32, 64));
        ABu B;
        B.u[0] = f2bf(__builtin_amdgcn_exp2f(s0[0] - mx));
        B.u[1] = f2bf(__builtin_amdgcn_exp2f(s0[1] - mx));
        B.u[2] = f2bf(__builtin_amdgcn_exp2f(s0[2] - mx));
        B.u[3] = f2bf(__builtin_amdgcn_exp2f(s0[3] - mx));
        B.u[4] = f2bf(__builtin_amdgcn_exp2f(s1[0] - mx));
        B.u[5] = f2bf(__builtin_amdgcn_exp2f(s1[1] - mx));
        B.u[6] = f2bf(__builtin_amdgcn_exp2f(s1[2] - mx));
        B.u[7] = f2bf(__builtin_amdgcn_exp2f(s1[3] - mx));
        f32x4 D0 = __builtin_amdgcn_mfma_f32_16x16x32_bf16(A0.b, B.b, z, 0, 0, 0);
        f32x4 D1 = __builtin_amdgcn_mfma_f32_16x16x32_bf16(A1.b, B.b, z, 0, 0, 0);
        const float* em = eb + (m + 1) * 33;
        #pragma unroll
        for (int i = 0; i < 4; ++i)
            s0[i] = mx + __builtin_amdgcn_logf(D0[i]) + em[i];
        s1[0] = ok0 ? (mx + __builtin_amdgcn_logf(D1[0]) + em[16]) : NEGF;
        s1[1] = ok1 ? (mx + __builtin_amdgcn_logf(D1[1]) + em[17]) : NEGF;
        s1[2] = ok2 ? (mx + __builtin_amdgcn_logf(D1[2]) + em[18]) : NEGF;
        s1[3] = ok3 ? (mx + __builtin_amdgcn_logf(D1[3]) + em[19]) : NEGF;
    }

    // logZ per column c
    float mx2 = fmaxf(fmaxf(fmaxf(s0[0], s0[1]), fmaxf(s0[2], s0[3])),
                      fmaxf(fmaxf(s1[0], s1[1]), fmaxf(s1[2], s1[3])));
    mx2 = fmaxf(mx2, __shfl_xor(mx2, 16, 64));
    mx2 = fmaxf(mx2, __shfl_xor(mx2, 32, 64));
    float sm = __builtin_amdgcn_exp2f(s0[0] - mx2) + __builtin_amdgcn_exp2f(s0[1] - mx2)
             + __builtin_amdgcn_exp2f(s0[2] - mx2) + __builtin_amdgcn_exp2f(s0[3] - mx2)
             + __builtin_amdgcn_exp2f(s1[0] - mx2) + __builtin_amdgcn_exp2f(s1[1] - mx2)
             + __builtin_amdgcn_exp2f(s1[2] - mx2) + __builtin_amdgcn_exp2f(s1[3] - mx2);
    sm += __shfl_xor(sm, 16, 64);
    sm += __shfl_xor(sm, 32, 64);
    const float logZ2 = mx2 + __builtin_amdgcn_logf(sm);

    // node + edge: lane (g,c) covers elem c's timesteps 5g..5g+4
    const int elem = blockIdx.x * 16 + c;
    const int ebase = elem * 20;
    float nd2 = 0.f, edn = 0.f;
    {
        int y[6];
        #pragma unroll
        for (int t = 0; t < 5; ++t) y[t] = Y[ebase + 5 * g + t];
        y[5] = (g < 3) ? Y[ebase + 5 * g + 5] : 0;
        #pragma unroll
        for (int t = 0; t < 5; ++t) {
            const int m = 5 * g + t;
            nd2 += e_lds[(c * 20 + m) * 33 + y[t]];
            if (m < 19) edn += t_lds[y[t] * 26 + y[t + 1]];
        }
    }

    float v = -LN2 * nd2 - edn;
    if (g == 0) v += LN2 * logZ2;
    #pragma unroll
    for (int d = 1; d <= 32; d <<= 1) v += __shfl_xor(v, d, 64);
    if (l == 0) atomicAdd(out, v);
}

extern "C" void kernel_launch(void* const* d_in, const int* in_sizes, int n_in,
                              void* d_out, int out_size, void* d_ws, size_t ws_size,
                              hipStream_t stream) {
    const float* X = (const float*)d_in[0];
    const int*   Y = (const int*)d_in[1];
    const float* W = (const float*)d_in[2];
    const float* T = (const float*)d_in[3];
    float* out = (float*)d_out;

    const int B = in_sizes[1] / 20;        // 8192
    const int nblocks = B / 16;            // 512

    hipMemsetAsync(out, 0, sizeof(float), stream);
    crf_kernel<<<nblocks, 256, 0, stream>>>(X, Y, W, T, out, B);
}